// Round 16
// baseline (237.806 us; speedup 1.0000x reference)
//
#include <hip/hip_runtime.h>
#include <hip/hip_bf16.h>
#include <math.h>

#define N_CELLS 65536
#define D_DIM   128
#define K_PROTO 2048

typedef __attribute__((ext_vector_type(8))) short bf16x8;
typedef __attribute__((ext_vector_type(4))) float f32x4;

// RTN-even float -> bf16 bit pattern
__device__ __forceinline__ unsigned int f2bf(float f) {
  unsigned int u = __float_as_uint(f);
  return ((u + 0x7FFFu + ((u >> 16) & 1u)) >> 16) & 0xFFFFu;
}

// ---- K1: row-normalize x -> z (NT float4 out) + zb (packed bf16) ----
__global__ __launch_bounds__(256) void normalize_k(
    const float* __restrict__ x, float* __restrict__ z,
    unsigned int* __restrict__ zb) {
  int tid = threadIdx.x;
  int sub = tid & 31;
  int row = blockIdx.x * 8 + (tid >> 5);
  const f32x4* xr = (const f32x4*)(x + (size_t)row * D_DIM);
  f32x4 v = xr[sub];
  float s = v.x * v.x + v.y * v.y + v.z * v.z + v.w * v.w;
  #pragma unroll
  for (int off = 1; off < 32; off <<= 1) s += __shfl_xor(s, off, 64);
  float inv = 1.0f / fmaxf(sqrtf(s), 1e-12f);
  f32x4 zv = v * inv;
  __builtin_nontemporal_store(zv, (f32x4*)(z + (size_t)row * D_DIM) + sub);
  unsigned int lo = (f2bf(zv.y) << 16) | f2bf(zv.x);
  unsigned int h2 = (f2bf(zv.w) << 16) | f2bf(zv.z);
  unsigned long long pk = ((unsigned long long)h2 << 32) | lo;
  *((unsigned long long*)(zb + (size_t)row * (D_DIM / 2)) + sub) = pk;
}

// ---- K2: W -> bf16 + ww norms; block 0 writes cvae ----
__global__ __launch_bounds__(256) void wprep_k(
    const float* __restrict__ W, unsigned int* __restrict__ wb,
    float* __restrict__ ww,
    const float* __restrict__ recon, const float* __restrict__ kl,
    const float* __restrict__ mmd, float* __restrict__ scal) {
  if (blockIdx.x == 0 && threadIdx.x == 0) {
    scal[0] = recon[0] + 0.5f * kl[0] + mmd[0];  // cvae_loss
  }
  int tid = threadIdx.x;
  int sub = tid & 31;
  int row = blockIdx.x * 8 + (tid >> 5);
  const f32x4* wr = (const f32x4*)(W + (size_t)row * D_DIM);
  f32x4 v = wr[sub];
  float s = v.x * v.x + v.y * v.y + v.z * v.z + v.w * v.w;
  #pragma unroll
  for (int off = 1; off < 32; off <<= 1) s += __shfl_xor(s, off, 64);
  if (sub == 0) ww[row] = s;
  unsigned int lo = (f2bf(v.y) << 16) | f2bf(v.x);
  unsigned int h2 = (f2bf(v.w) << 16) | f2bf(v.z);
  unsigned long long pk = ((unsigned long long)h2 << 32) | lo;
  *((unsigned long long*)(wb + (size_t)row * (D_DIM / 2)) + sub) = pk;
}

// ---- K3: R9 structure, 8 waves/block: 64x32 sub-tile per wave.
//      Shorter compute phase + 2x wider store issue. ----
__global__ __launch_bounds__(512, 4) void gemm_k(
    const unsigned short* __restrict__ zb, const unsigned short* __restrict__ wb,
    const float* __restrict__ ww, float* __restrict__ logits,
    float* __restrict__ rowmin_part, float* __restrict__ colmax_part) {
  __shared__ float cs[128 * 128];   // 64 KiB C-tile staging
  __shared__ float rmin[4][128];    // per-colquarter row mins
  __shared__ float cmx[2][128];     // per-rowhalf col maxes

  int bid = blockIdx.x;
  int swz = (bid & 7) * 1024 + (bid >> 3);
  int nt  = swz & 15;
  int mt  = swz >> 4;

  int tid  = threadIdx.x;
  int lane = tid & 63;
  int wid  = tid >> 6;              // 0..7
  int wr   = wid >> 2;              // 0..1  (row half)
  int wc   = wid & 3;               // 0..3  (col quarter)
  int wrow = wr * 64;
  int wcol = wc * 32;
  int l15  = lane & 15;
  int hi   = lane >> 4;
  int l31  = lane & 31;
  int rsub = lane >> 5;

  const char* Abase = (const char*)zb + ((size_t)(mt * 128 + wrow + l15) * 256 + hi * 16);
  const char* Bbase = (const char*)wb + ((size_t)(nt * 128 + wcol + l15) * 256 + hi * 16);

  f32x4 acc[4][2];
  #pragma unroll
  for (int i = 0; i < 4; ++i)
    #pragma unroll
    for (int j = 0; j < 2; ++j)
      acc[i][j] = f32x4{0.f, 0.f, 0.f, 0.f};

  #pragma unroll
  for (int kk = 0; kk < 4; ++kk) {
    bf16x8 a[4], b[2];
    #pragma unroll
    for (int i = 0; i < 4; ++i) a[i] = *(const bf16x8*)(Abase + i * 4096 + kk * 64);
    #pragma unroll
    for (int j = 0; j < 2; ++j) b[j] = *(const bf16x8*)(Bbase + j * 4096 + kk * 64);
    // SWAPPED: C/D reg axis = protos. cell = wrow+i*16+l15, proto = wcol+j*16+hi*4+r
    #pragma unroll
    for (int i = 0; i < 4; ++i)
      #pragma unroll
      for (int j = 0; j < 2; ++j)
        acc[i][j] = __builtin_amdgcn_mfma_f32_16x16x32_bf16(b[j], a[i], acc[i][j], 0, 0, 0);
  }

  int gcolbase = nt * 128 + wcol;
  f32x4 wwj[2];
  #pragma unroll
  for (int j = 0; j < 2; ++j)
    wwj[j] = *(const f32x4*)(ww + gcolbase + j * 16 + hi * 4);

  // rowmin(ww - 2L): reduce over j,r in-reg then hi lanes; publish per col-quarter
  #pragma unroll
  for (int i = 0; i < 4; ++i) {
    float vmin = 1e30f;
    #pragma unroll
    for (int j = 0; j < 2; ++j)
      #pragma unroll
      for (int r = 0; r < 4; ++r) vmin = fminf(vmin, wwj[j][r] - 2.0f * acc[i][j][r]);
    vmin = fminf(vmin, __shfl_xor(vmin, 16, 64));
    vmin = fminf(vmin, __shfl_xor(vmin, 32, 64));
    if (hi == 0) rmin[wc][wrow + i * 16 + l15] = vmin;
  }

  // colmax(L): reduce over i regs + l15 lanes; publish per row-half
  #pragma unroll
  for (int j = 0; j < 2; ++j) {
    f32x4 m = acc[0][j];
    #pragma unroll
    for (int i = 1; i < 4; ++i)
      #pragma unroll
      for (int r = 0; r < 4; ++r) m[r] = fmaxf(m[r], acc[i][j][r]);
    #pragma unroll
    for (int s2 = 1; s2 < 16; s2 <<= 1)
      #pragma unroll
      for (int r = 0; r < 4; ++r) m[r] = fmaxf(m[r], __shfl_xor(m[r], s2, 64));
    if (l15 == 0)
      *(f32x4*)&cmx[wr][wcol + j * 16 + hi * 4] = m;
  }

  // stage C sub-tile -> cs (granule-XOR swizzle)
  #pragma unroll
  for (int i = 0; i < 4; ++i) {
    int row = wrow + i * 16 + l15;
    #pragma unroll
    for (int j = 0; j < 2; ++j) {
      int g  = (wcol >> 2) + j * 4 + hi;
      int pg = g ^ ((row & 7) << 2);
      *(f32x4*)((char*)cs + row * 512 + pg * 16) = acc[i][j];
    }
  }
  __syncthreads();

  // combined partial writes (no atomics)
  if (tid < 128) {
    float v0 = fminf(rmin[0][tid], rmin[1][tid]);
    float v1 = fminf(rmin[2][tid], rmin[3][tid]);
    rowmin_part[(size_t)nt * N_CELLS + mt * 128 + tid] = fminf(v0, v1);
  } else if (tid < 256) {
    int c = tid - 128;
    colmax_part[(size_t)mt * K_PROTO + nt * 128 + c] =
        fmaxf(cmx[0][c], cmx[1][c]);
  }

  // NT store sweep: 8 waves x 8 iters x 2 rows x 512 B contiguous
  #pragma unroll
  for (int it = 0; it < 8; ++it) {
    int row = it * 16 + wid * 2 + rsub;
    int pg  = l31 ^ ((row & 7) << 2);
    f32x4 c = *(const f32x4*)((const char*)cs + row * 512 + pg * 16);
    size_t grow = (size_t)mt * 128 + row;
    __builtin_nontemporal_store(c, (f32x4*)(logits + grow * K_PROTO + nt * 128 + l31 * 4));
  }
}

// ---- K4: rowmin over 16 nt-planes -> sqrt -> per-block sum ----
__global__ __launch_bounds__(1024) void prop1_k(
    const float* __restrict__ rowmin_part, float* __restrict__ prop_part) {
  __shared__ float sbuf[16];
  int slot = blockIdx.x * 1024 + threadIdx.x;   // 16384 float4 slots
  f32x4 v = *(const f32x4*)(rowmin_part + (size_t)slot * 4);
  #pragma unroll
  for (int p = 1; p < 16; ++p) {
    f32x4 u = *(const f32x4*)(rowmin_part + (size_t)p * N_CELLS + (size_t)slot * 4);
    #pragma unroll
    for (int r = 0; r < 4; ++r) v[r] = fminf(v[r], u[r]);
  }
  float s = 0.f;
  #pragma unroll
  for (int r = 0; r < 4; ++r) s += sqrtf(fmaxf(1.0f + v[r], 0.0f));
  #pragma unroll
  for (int off = 1; off < 64; off <<= 1) s += __shfl_xor(s, off, 64);
  int wv = threadIdx.x >> 6, lane = threadIdx.x & 63;
  if (lane == 0) sbuf[wv] = s;
  __syncthreads();
  if (threadIdx.x == 0) {
    float t = 0.f;
    #pragma unroll
    for (int w = 0; w < 16; ++w) t += sbuf[w];
    prop_part[blockIdx.x] = t;
  }
}

// ---- K5: colmax over 512 mt-planes -> sqrt(1+ww-2max) -> per-block sum ----
__global__ __launch_bounds__(1024) void emb1_k(
    const float* __restrict__ colmax_part, const float* __restrict__ ww,
    float* __restrict__ emb_part) {
  __shared__ float buf[8][128];
  __shared__ float sbuf[2];
  int t   = threadIdx.x;
  int col = blockIdx.x * 128 + (t & 127);
  int seg = t >> 7;                      // 0..7, 64 mt each
  float m = -1e30f;
  for (int k = 0; k < 64; ++k)
    m = fmaxf(m, colmax_part[(size_t)(seg * 64 + k) * K_PROTO + col]);
  buf[seg][t & 127] = m;
  __syncthreads();
  if (t < 128) {
    float tot = buf[0][t];
    #pragma unroll
    for (int s2 = 1; s2 < 8; ++s2) tot = fmaxf(tot, buf[s2][t]);
    float val = sqrtf(fmaxf(1.0f + ww[col] - 2.0f * tot, 0.0f));
    #pragma unroll
    for (int off = 1; off < 64; off <<= 1) val += __shfl_xor(val, off, 64);
    if ((t & 63) == 0) sbuf[t >> 6] = val;
  }
  __syncthreads();
  if (t == 0) emb_part[blockIdx.x] = sbuf[0] + sbuf[1];
}

// ---- K6: final scalars ----
__global__ __launch_bounds__(64) void final_k(
    const float* __restrict__ prop_part, const float* __restrict__ emb_part,
    float* __restrict__ scal) {
  if (threadIdx.x == 0) {
    float p = 0.f, e = 0.f;
    #pragma unroll
    for (int i = 0; i < 16; ++i) { p += prop_part[i]; e += emb_part[i]; }
    scal[1] = p * (1.0f / N_CELLS);
    scal[2] = e * (1.0f / K_PROTO);
  }
}

extern "C" void kernel_launch(void* const* d_in, const int* in_sizes, int n_in,
                              void* d_out, int out_size, void* d_ws, size_t ws_size,
                              hipStream_t stream) {
  const float* x     = (const float*)d_in[0];
  const float* W     = (const float*)d_in[1];
  const float* recon = (const float*)d_in[2];
  const float* kl    = (const float*)d_in[3];
  const float* mmd   = (const float*)d_in[4];

  float* out    = (float*)d_out;
  float* z      = out;
  float* logits = out + (size_t)N_CELLS * D_DIM;
  float* scal   = logits + (size_t)N_CELLS * K_PROTO;  // [cvae, prop, emb]

  char* ws = (char*)d_ws;
  unsigned int* zb = (unsigned int*)ws;                     // 16 MiB packed bf16
  size_t off = (size_t)N_CELLS * D_DIM * 2;
  unsigned int* wb = (unsigned int*)(ws + off);             // 0.5 MiB
  off += (size_t)K_PROTO * D_DIM * 2;
  float* ww = (float*)(ws + off);                           // 8 KiB
  off += (size_t)K_PROTO * 4;
  float* rowmin_part = (float*)(ws + off);                  // 16 x 65536 f32 = 4 MiB
  off += (size_t)16 * N_CELLS * 4;
  float* colmax_part = (float*)(ws + off);                  // 512 x 2048 f32 = 4 MiB
  off += (size_t)512 * K_PROTO * 4;
  float* prop_part = (float*)(ws + off);                    // 16 f32
  off += 16 * 4;
  float* emb_part = (float*)(ws + off);                     // 16 f32

  normalize_k<<<N_CELLS / 8, 256, 0, stream>>>(x, z, zb);
  wprep_k<<<K_PROTO / 8, 256, 0, stream>>>(W, wb, ww, recon, kl, mmd, scal);
  gemm_k<<<(N_CELLS / 128) * (K_PROTO / 128), 512, 0, stream>>>(
      (const unsigned short*)zb, (const unsigned short*)wb, ww, logits,
      rowmin_part, colmax_part);
  prop1_k<<<16, 1024, 0, stream>>>(rowmin_part, prop_part);
  emb1_k<<<16, 1024, 0, stream>>>(colmax_part, ww, emb_part);
  final_k<<<1, 64, 0, stream>>>(prop_part, emb_part, scal);
}

// Round 17
// 193.862 us; speedup vs baseline: 1.2267x; 1.2267x over previous
//
#include <hip/hip_runtime.h>
#include <hip/hip_bf16.h>
#include <math.h>

#define N_CELLS 65536
#define D_DIM   128
#define K_PROTO 2048

typedef __attribute__((ext_vector_type(8))) short bf16x8;
typedef __attribute__((ext_vector_type(4))) float f32x4;

// RTN-even float -> bf16 bit pattern
__device__ __forceinline__ unsigned int f2bf(float f) {
  unsigned int u = __float_as_uint(f);
  return ((u + 0x7FFFu + ((u >> 16) & 1u)) >> 16) & 0xFFFFu;
}

// LDS-only barrier: lgkmcnt(0) + s_barrier, leaves NT stores in flight.
__device__ __forceinline__ void lds_barrier() {
  __builtin_amdgcn_sched_barrier(0);
  asm volatile("s_waitcnt lgkmcnt(0)" ::: "memory");
  __builtin_amdgcn_sched_barrier(0);
  __builtin_amdgcn_s_barrier();
  __builtin_amdgcn_sched_barrier(0);
}

// ---- K1: row-normalize x -> z (NT float4 out) + zb (packed bf16) ----
__global__ __launch_bounds__(256) void normalize_k(
    const float* __restrict__ x, float* __restrict__ z,
    unsigned int* __restrict__ zb) {
  int tid = threadIdx.x;
  int sub = tid & 31;
  int row = blockIdx.x * 8 + (tid >> 5);
  const f32x4* xr = (const f32x4*)(x + (size_t)row * D_DIM);
  f32x4 v = xr[sub];
  float s = v.x * v.x + v.y * v.y + v.z * v.z + v.w * v.w;
  #pragma unroll
  for (int off = 1; off < 32; off <<= 1) s += __shfl_xor(s, off, 64);
  float inv = 1.0f / fmaxf(sqrtf(s), 1e-12f);
  f32x4 zv = v * inv;
  __builtin_nontemporal_store(zv, (f32x4*)(z + (size_t)row * D_DIM) + sub);
  unsigned int lo = (f2bf(zv.y) << 16) | f2bf(zv.x);
  unsigned int h2 = (f2bf(zv.w) << 16) | f2bf(zv.z);
  unsigned long long pk = ((unsigned long long)h2 << 32) | lo;
  *((unsigned long long*)(zb + (size_t)row * (D_DIM / 2)) + sub) = pk;
}

// ---- K2: W -> bf16 + ww norms; block 0 writes cvae ----
__global__ __launch_bounds__(256) void wprep_k(
    const float* __restrict__ W, unsigned int* __restrict__ wb,
    float* __restrict__ ww,
    const float* __restrict__ recon, const float* __restrict__ kl,
    const float* __restrict__ mmd, float* __restrict__ scal) {
  if (blockIdx.x == 0 && threadIdx.x == 0) {
    scal[0] = recon[0] + 0.5f * kl[0] + mmd[0];  // cvae_loss
  }
  int tid = threadIdx.x;
  int sub = tid & 31;
  int row = blockIdx.x * 8 + (tid >> 5);
  const f32x4* wr = (const f32x4*)(W + (size_t)row * D_DIM);
  f32x4 v = wr[sub];
  float s = v.x * v.x + v.y * v.y + v.z * v.z + v.w * v.w;
  #pragma unroll
  for (int off = 1; off < 32; off <<= 1) s += __shfl_xor(s, off, 64);
  if (sub == 0) ww[row] = s;
  unsigned int lo = (f2bf(v.y) << 16) | f2bf(v.x);
  unsigned int h2 = (f2bf(v.w) << 16) | f2bf(v.z);
  unsigned long long pk = ((unsigned long long)h2 << 32) | lo;
  *((unsigned long long*)(wb + (size_t)row * (D_DIM / 2)) + sub) = pk;
}

// ---- K3: R9 structure + half-tile staging (32 KiB LDS -> 4 blocks/CU).
//      No vmcnt wait after any store; lgkm-only barriers. ----
__global__ __launch_bounds__(256, 4) void gemm_k(
    const unsigned short* __restrict__ zb, const unsigned short* __restrict__ wb,
    const float* __restrict__ ww, float* __restrict__ logits,
    float* __restrict__ rowmin_part, float* __restrict__ colmax_part) {
  __shared__ float cs[64 * 128];    // 32 KiB half-tile staging
  __shared__ float rmin[2][128];    // per-colhalf row mins
  __shared__ float cmx[2][128];     // per-rowhalf col maxes

  int bid = blockIdx.x;
  int swz = (bid & 7) * 1024 + (bid >> 3);
  int nt  = swz & 15;
  int mt  = swz >> 4;

  int tid  = threadIdx.x;
  int lane = tid & 63;
  int wid  = tid >> 6;
  int wrow = (wid >> 1) * 64;
  int wcol = (wid & 1) * 64;
  int l15  = lane & 15;
  int hi   = lane >> 4;
  int l31  = lane & 31;
  int rsub = lane >> 5;

  const char* Abase = (const char*)zb + ((size_t)(mt * 128 + wrow + l15) * 256 + hi * 16);
  const char* Bbase = (const char*)wb + ((size_t)(nt * 128 + wcol + l15) * 256 + hi * 16);

  f32x4 acc[4][4];
  #pragma unroll
  for (int i = 0; i < 4; ++i)
    #pragma unroll
    for (int j = 0; j < 4; ++j)
      acc[i][j] = f32x4{0.f, 0.f, 0.f, 0.f};

  #pragma unroll
  for (int kk = 0; kk < 4; ++kk) {
    bf16x8 a[4], b[4];
    #pragma unroll
    for (int i = 0; i < 4; ++i) a[i] = *(const bf16x8*)(Abase + i * 4096 + kk * 64);
    #pragma unroll
    for (int j = 0; j < 4; ++j) b[j] = *(const bf16x8*)(Bbase + j * 4096 + kk * 64);
    // SWAPPED: C/D reg axis = protos. cell = wrow+i*16+l15, proto = wcol+j*16+hi*4+r
    #pragma unroll
    for (int i = 0; i < 4; ++i)
      #pragma unroll
      for (int j = 0; j < 4; ++j)
        acc[i][j] = __builtin_amdgcn_mfma_f32_16x16x32_bf16(b[j], a[i], acc[i][j], 0, 0, 0);
  }

  int gcolbase = nt * 128 + wcol;
  f32x4 wwj[4];
  #pragma unroll
  for (int j = 0; j < 4; ++j)
    wwj[j] = *(const f32x4*)(ww + gcolbase + j * 16 + hi * 4);

  // rowmin(ww - 2L) -> rmin[colhalf][row]
  #pragma unroll
  for (int i = 0; i < 4; ++i) {
    float vmin = 1e30f;
    #pragma unroll
    for (int j = 0; j < 4; ++j)
      #pragma unroll
      for (int r = 0; r < 4; ++r) vmin = fminf(vmin, wwj[j][r] - 2.0f * acc[i][j][r]);
    vmin = fminf(vmin, __shfl_xor(vmin, 16, 64));
    vmin = fminf(vmin, __shfl_xor(vmin, 32, 64));
    if (hi == 0) rmin[wid & 1][wrow + i * 16 + l15] = vmin;
  }

  // colmax(L) -> cmx[rowhalf][col]
  #pragma unroll
  for (int j = 0; j < 4; ++j) {
    f32x4 m = acc[0][j];
    #pragma unroll
    for (int i = 1; i < 4; ++i)
      #pragma unroll
      for (int r = 0; r < 4; ++r) m[r] = fmaxf(m[r], acc[i][j][r]);
    #pragma unroll
    for (int s2 = 1; s2 < 16; s2 <<= 1)
      #pragma unroll
      for (int r = 0; r < 4; ++r) m[r] = fmaxf(m[r], __shfl_xor(m[r], s2, 64));
    if (l15 == 0)
      *(f32x4*)&cmx[wid >> 1][wcol + j * 16 + hi * 4] = m;
  }

  // stage half 0 (rows 0-63): waves 0,1 (wrow==0); local r = i*16+l15
  if (wrow == 0) {
    #pragma unroll
    for (int i = 0; i < 4; ++i) {
      int r = i * 16 + l15;
      #pragma unroll
      for (int j = 0; j < 4; ++j) {
        int g  = (wcol >> 2) + j * 4 + hi;
        int pg = g ^ ((r & 7) << 2);
        *(f32x4*)((char*)cs + r * 512 + pg * 16) = acc[i][j];
      }
    }
  }
  lds_barrier();  // rmin/cmx/half0 staged

  // partial writes (issued before store bursts; tiny)
  if (tid < 128) {
    rowmin_part[(size_t)nt * N_CELLS + mt * 128 + tid] =
        fminf(rmin[0][tid], rmin[1][tid]);
  } else {
    int c = tid - 128;
    colmax_part[(size_t)mt * K_PROTO + nt * 128 + c] =
        fmaxf(cmx[0][c], cmx[1][c]);
  }

  // store half 0: 2 rows x 512 B contiguous per wave-instruction, NT
  #pragma unroll
  for (int it = 0; it < 8; ++it) {
    int r  = it * 8 + wid * 2 + rsub;       // 0..63
    int pg = l31 ^ ((r & 7) << 2);
    f32x4 c = *(const f32x4*)((const char*)cs + r * 512 + pg * 16);
    size_t grow = (size_t)mt * 128 + r;
    __builtin_nontemporal_store(c, (f32x4*)(logits + grow * K_PROTO + nt * 128 + l31 * 4));
  }

  lds_barrier();  // all ds_reads of half 0 done -> cs reusable

  // stage half 1 (rows 64-127): waves 2,3 (wrow==64)
  if (wrow == 64) {
    #pragma unroll
    for (int i = 0; i < 4; ++i) {
      int r = i * 16 + l15;
      #pragma unroll
      for (int j = 0; j < 4; ++j) {
        int g  = (wcol >> 2) + j * 4 + hi;
        int pg = g ^ ((r & 7) << 2);
        *(f32x4*)((char*)cs + r * 512 + pg * 16) = acc[i][j];
      }
    }
  }
  lds_barrier();  // half1 staged

  // store half 1
  #pragma unroll
  for (int it = 0; it < 8; ++it) {
    int r  = it * 8 + wid * 2 + rsub;       // 0..63
    int pg = l31 ^ ((r & 7) << 2);
    f32x4 c = *(const f32x4*)((const char*)cs + r * 512 + pg * 16);
    size_t grow = (size_t)mt * 128 + 64 + r;
    __builtin_nontemporal_store(c, (f32x4*)(logits + grow * K_PROTO + nt * 128 + l31 * 4));
  }
}

// ---- K4: rowmin over 16 nt-planes -> sqrt -> per-block sum ----
__global__ __launch_bounds__(1024) void prop1_k(
    const float* __restrict__ rowmin_part, float* __restrict__ prop_part) {
  __shared__ float sbuf[16];
  int slot = blockIdx.x * 1024 + threadIdx.x;   // 16384 float4 slots
  f32x4 v = *(const f32x4*)(rowmin_part + (size_t)slot * 4);
  #pragma unroll
  for (int p = 1; p < 16; ++p) {
    f32x4 u = *(const f32x4*)(rowmin_part + (size_t)p * N_CELLS + (size_t)slot * 4);
    #pragma unroll
    for (int r = 0; r < 4; ++r) v[r] = fminf(v[r], u[r]);
  }
  float s = 0.f;
  #pragma unroll
  for (int r = 0; r < 4; ++r) s += sqrtf(fmaxf(1.0f + v[r], 0.0f));
  #pragma unroll
  for (int off = 1; off < 64; off <<= 1) s += __shfl_xor(s, off, 64);
  int wv = threadIdx.x >> 6, lane = threadIdx.x & 63;
  if (lane == 0) sbuf[wv] = s;
  __syncthreads();
  if (threadIdx.x == 0) {
    float t = 0.f;
    #pragma unroll
    for (int w = 0; w < 16; ++w) t += sbuf[w];
    prop_part[blockIdx.x] = t;
  }
}

// ---- K5: colmax over 512 mt-planes -> sqrt(1+ww-2max) -> per-block sum ----
__global__ __launch_bounds__(1024) void emb1_k(
    const float* __restrict__ colmax_part, const float* __restrict__ ww,
    float* __restrict__ emb_part) {
  __shared__ float buf[8][128];
  __shared__ float sbuf[2];
  int t   = threadIdx.x;
  int col = blockIdx.x * 128 + (t & 127);
  int seg = t >> 7;                      // 0..7, 64 mt each
  float m = -1e30f;
  for (int k = 0; k < 64; ++k)
    m = fmaxf(m, colmax_part[(size_t)(seg * 64 + k) * K_PROTO + col]);
  buf[seg][t & 127] = m;
  __syncthreads();
  if (t < 128) {
    float tot = buf[0][t];
    #pragma unroll
    for (int s2 = 1; s2 < 8; ++s2) tot = fmaxf(tot, buf[s2][t]);
    float val = sqrtf(fmaxf(1.0f + ww[col] - 2.0f * tot, 0.0f));
    #pragma unroll
    for (int off = 1; off < 64; off <<= 1) val += __shfl_xor(val, off, 64);
    if ((t & 63) == 0) sbuf[t >> 6] = val;
  }
  __syncthreads();
  if (t == 0) emb_part[blockIdx.x] = sbuf[0] + sbuf[1];
}

// ---- K6: final scalars ----
__global__ __launch_bounds__(64) void final_k(
    const float* __restrict__ prop_part, const float* __restrict__ emb_part,
    float* __restrict__ scal) {
  if (threadIdx.x == 0) {
    float p = 0.f, e = 0.f;
    #pragma unroll
    for (int i = 0; i < 16; ++i) { p += prop_part[i]; e += emb_part[i]; }
    scal[1] = p * (1.0f / N_CELLS);
    scal[2] = e * (1.0f / K_PROTO);
  }
}

extern "C" void kernel_launch(void* const* d_in, const int* in_sizes, int n_in,
                              void* d_out, int out_size, void* d_ws, size_t ws_size,
                              hipStream_t stream) {
  const float* x     = (const float*)d_in[0];
  const float* W     = (const float*)d_in[1];
  const float* recon = (const float*)d_in[2];
  const float* kl    = (const float*)d_in[3];
  const float* mmd   = (const float*)d_in[4];

  float* out    = (float*)d_out;
  float* z      = out;
  float* logits = out + (size_t)N_CELLS * D_DIM;
  float* scal   = logits + (size_t)N_CELLS * K_PROTO;  // [cvae, prop, emb]

  char* ws = (char*)d_ws;
  unsigned int* zb = (unsigned int*)ws;                     // 16 MiB packed bf16
  size_t off = (size_t)N_CELLS * D_DIM * 2;
  unsigned int* wb = (unsigned int*)(ws + off);             // 0.5 MiB
  off += (size_t)K_PROTO * D_DIM * 2;
  float* ww = (float*)(ws + off);                           // 8 KiB
  off += (size_t)K_PROTO * 4;
  float* rowmin_part = (float*)(ws + off);                  // 16 x 65536 f32 = 4 MiB
  off += (size_t)16 * N_CELLS * 4;
  float* colmax_part = (float*)(ws + off);                  // 512 x 2048 f32 = 4 MiB
  off += (size_t)512 * K_PROTO * 4;
  float* prop_part = (float*)(ws + off);                    // 16 f32
  off += 16 * 4;
  float* emb_part = (float*)(ws + off);                     // 16 f32

  normalize_k<<<N_CELLS / 8, 256, 0, stream>>>(x, z, zb);
  wprep_k<<<K_PROTO / 8, 256, 0, stream>>>(W, wb, ww, recon, kl, mmd, scal);
  gemm_k<<<(N_CELLS / 128) * (K_PROTO / 128), 256, 0, stream>>>(
      (const unsigned short*)zb, (const unsigned short*)wb, ww, logits,
      rowmin_part, colmax_part);
  prop1_k<<<16, 1024, 0, stream>>>(rowmin_part, prop_part);
  emb1_k<<<16, 1024, 0, stream>>>(colmax_part, ww, emb_part);
  final_k<<<1, 64, 0, stream>>>(prop_part, emb_part, scal);
}